// Round 23
// baseline (66.292 us; speedup 1.0000x reference)
//
#include <hip/hip_runtime.h>
#include <hip/hip_fp16.h>
#include <math.h>

#define BATCH 131072
#define NSTEPS 256
#define NPAIRS 128         // one poly row per 2 steps (even steps)
#define NCOEF 16           // Chebyshev coefficients per row
#define MU_C 0.72134752044448170367f   // (mu - sigma^2/2)/ln2 = 0.5/ln2
#define SD_C 1.4426950408889634f       // sigma/ln2

using f32x2 = __attribute__((ext_vector_type(2))) float;

__device__ __forceinline__ float fast_exp(float x) {
    return __builtin_amdgcn_exp2f(x * 1.44269504088896340736f);
}
__device__ __forceinline__ float fast_rcp(float x) {
    return __builtin_amdgcn_rcpf(x);
}
__device__ __forceinline__ float sigmoidf_fast(float x) {
    return fast_rcp(1.0f + fast_exp(-x));
}

#define REP32(M) M(0) M(1) M(2) M(3) M(4) M(5) M(6) M(7) \
                 M(8) M(9) M(10) M(11) M(12) M(13) M(14) M(15) \
                 M(16) M(17) M(18) M(19) M(20) M(21) M(22) M(23) \
                 M(24) M(25) M(26) M(27) M(28) M(29) M(30) M(31)

#define REP16(M) M(0) M(1) M(2) M(3) M(4) M(5) M(6) M(7) \
                 M(8) M(9) M(10) M(11) M(12) M(13) M(14) M(15)

// pairs in a 16-step chunk: M(pair, even-noise-reg, odd-noise-reg)
#define REPP(M) M(0,0,1) M(1,2,3) M(2,4,5) M(3,6,7) \
                M(4,8,9) M(5,10,11) M(6,12,13) M(7,14,15)

// Shared MLP+tangent body (see R4). Produces h and pre-sigmoid tangent acc.
#define MLP_BODY(W1r, B1, W2r, B2, W3r, b3v, t, s, sd, H, HACC) \
    { \
        const float __t = (t), __s = (s), __sd = (sd); \
        f32x2 acc2 = {(b3v), 0.0f}; \
        REP32(MLP_L1) \
        REP32(MLP_ROW) \
        H = sigmoidf_fast(acc2.x); \
        HACC = acc2.y; \
    }

#define MLP_L1(j) f32x2 at##j; { \
    const float2 wv = W1r[j]; \
    const float z  = fmaf(wv.x, __t, fmaf(wv.y, __s, B1[j])); \
    const float zd = wv.y * __sd; \
    const float sg = sigmoidf_fast(z); \
    const float da = sg * (1.0f + z * (1.0f - sg)); \
    at##j = (f32x2){z * sg, da * zd}; }

#define MLP_ROW(j) { \
    const float4 q0 = W2r[(j) * 8 + 0]; \
    const float4 q1 = W2r[(j) * 8 + 1]; \
    const float4 q2 = W2r[(j) * 8 + 2]; \
    const float4 q3 = W2r[(j) * 8 + 3]; \
    const float4 q4 = W2r[(j) * 8 + 4]; \
    const float4 q5 = W2r[(j) * 8 + 5]; \
    const float4 q6 = W2r[(j) * 8 + 6]; \
    const float4 q7 = W2r[(j) * 8 + 7]; \
    f32x2 zza = {B2[j], 0.0f}; \
    f32x2 zzb = {0.0f, 0.0f}; \
    zza += (f32x2){q0.x, q0.x} * at0;  zzb += (f32x2){q0.y, q0.y} * at1; \
    zza += (f32x2){q0.z, q0.z} * at2;  zzb += (f32x2){q0.w, q0.w} * at3; \
    zza += (f32x2){q1.x, q1.x} * at4;  zzb += (f32x2){q1.y, q1.y} * at5; \
    zza += (f32x2){q1.z, q1.z} * at6;  zzb += (f32x2){q1.w, q1.w} * at7; \
    zza += (f32x2){q2.x, q2.x} * at8;  zzb += (f32x2){q2.y, q2.y} * at9; \
    zza += (f32x2){q2.z, q2.z} * at10; zzb += (f32x2){q2.w, q2.w} * at11; \
    zza += (f32x2){q3.x, q3.x} * at12; zzb += (f32x2){q3.y, q3.y} * at13; \
    zza += (f32x2){q3.z, q3.z} * at14; zzb += (f32x2){q3.w, q3.w} * at15; \
    zza += (f32x2){q4.x, q4.x} * at16; zzb += (f32x2){q4.y, q4.y} * at17; \
    zza += (f32x2){q4.z, q4.z} * at18; zzb += (f32x2){q4.w, q4.w} * at19; \
    zza += (f32x2){q5.x, q5.x} * at20; zzb += (f32x2){q5.y, q5.y} * at21; \
    zza += (f32x2){q5.z, q5.z} * at22; zzb += (f32x2){q5.w, q5.w} * at23; \
    zza += (f32x2){q6.x, q6.x} * at24; zzb += (f32x2){q6.y, q6.y} * at25; \
    zza += (f32x2){q6.z, q6.z} * at26; zzb += (f32x2){q6.w, q6.w} * at27; \
    zza += (f32x2){q7.x, q7.x} * at28; zzb += (f32x2){q7.y, q7.y} * at29; \
    zza += (f32x2){q7.z, q7.z} * at30; zzb += (f32x2){q7.w, q7.w} * at31; \
    const f32x2 zzt = zza + zzb; \
    const float zv  = zzt.x; \
    const float sg  = sigmoidf_fast(zv); \
    const float da  = sg * (1.0f + zv * (1.0f - sg)); \
    const float w3  = W3r[j]; \
    acc2 += (f32x2){w3, w3} * (f32x2){zv * sg, da * zzt.y}; \
}

// ---------------------------------------------------------------------------
// Kernel 1: Chebyshev fit.  Block = 16 rows x 16 nodes.  Each thread runs
// the MLP at node x_j = cos(pi(j+0.5)/16) of row p (t = ts[2p], s = 2^(mu +
// 6*x_j*sd)), then the block does the 16-point DCT:
//   c_k = (2/16) sum_j h_j cos(pi k (j+0.5)/16),  c_0 halved.
// ---------------------------------------------------------------------------
__global__ __launch_bounds__(256) void fit_kernel(
    const float* __restrict__ ts,
    const float* __restrict__ W1, const float* __restrict__ b1,
    const float* __restrict__ W2, const float* __restrict__ b2,
    const float* __restrict__ W3, const float* __restrict__ b3,
    float* __restrict__ C)             // (NPAIRS, NCOEF)
{
    __shared__ __align__(16) float sW1[64];
    __shared__ float sb1[32];
    __shared__ __align__(16) float sW2[1024];
    __shared__ float sb2[32];
    __shared__ float sW3[32];
    __shared__ float sb3[1];
    __shared__ float Hs[16][17];
    __shared__ float cosm[256];        // cosm[k*16+j] = cos(pi k (j+0.5)/16)

    const int tid = threadIdx.x;
    for (int i = tid; i < 1024; i += 256) sW2[i] = W2[i];
    if (tid < 64) sW1[tid] = W1[tid];
    if (tid < 32) { sb1[tid] = b1[tid]; sb2[tid] = b2[tid]; sW3[tid] = W3[tid]; }
    if (tid == 0) sb3[0] = b3[0];
    {
        const int k = tid >> 4, j = tid & 15;
        cosm[tid] = cosf(3.14159265358979f * (float)k * ((float)j + 0.5f)
                         * 0.0625f);
    }
    __syncthreads();

    const float2* W1r = (const float2*)sW1;
    const float*  B1  = sb1;
    const float4* W2r = (const float4*)sW2;
    const float*  B2  = sb2;
    const float*  W3r = sW3;
    const float   b3v = sb3[0];

    const int lp = tid >> 4;           // row within block
    const int j  = tid & 15;           // node index
    const int p  = blockIdx.x * 16 + lp;

    const float t  = ts[2 * p];
    const float mu = MU_C * t;
    const float sd = SD_C * __builtin_sqrtf(t) + 1e-4f;
    const float xj = cosm[16 + j];     // k=1 row = the nodes
    const float s  = __builtin_amdgcn_exp2f(fmaf(6.0f * xj, sd, mu));

    float h, hacc;
    MLP_BODY(W1r, B1, W2r, B2, W3r, b3v, t, s, 1.0f, h, hacc)
    (void)hacc;
    Hs[lp][j] = h;
    __syncthreads();

    // DCT: this thread computes coefficient k = j of row lp
    const int k = j;
    float c = 0.0f;
    #pragma unroll
    for (int jj = 0; jj < 16; ++jj)
        c = fmaf(Hs[lp][jj], cosm[k * 16 + jj], c);
    c *= 0.125f;                       // 2/16
    if (k == 0) c *= 0.5f;
    C[p * NCOEF + k] = c;
}

// ---------------------------------------------------------------------------
// Kernel 2: SDE path integration, GATHER-FREE.  Per pair: exact 2-step
// s-chain, then h = P(x), q = P'(x)*qs via dual Clenshaw on LDS-broadcast
// coefficients (wave-uniform address -> no conflicts, no L2 traffic).
// Odd step advances h along its tangent (R21).  NOTE: Clenshaw locals carry
// unique suffixes -- R22's NaN was `const float x2 = x2 + x2` for pair 2.
// ---------------------------------------------------------------------------
__global__ __launch_bounds__(256, 2) void path_kernel(
    const float* __restrict__ noise,   // (NSTEPS, BATCH)
    const float* __restrict__ ts,      // (NSTEPS+1)
    const float* __restrict__ wq,      // scalar
    const float* __restrict__ C,       // (NPAIRS, NCOEF)
    float* __restrict__ out)           // (BATCH)
{
    __shared__ float4 sPc[NPAIRS];     // {dt0, sqrt(dt0), dt1, sqrt(dt1)}
    __shared__ float4 sQc[NPAIRS];     // {cx, wx, qs, 0}: x = log2(s)*wx + cx
    __shared__ float  sC[NPAIRS * NCOEF];   // 8 KB coeffs
    const int tid = threadIdx.x;
    if (tid < NPAIRS) {
        const int p = tid;
        const float t0  = ts[2 * p];
        const float dt0 = ts[2 * p + 1] - t0;
        const float dt1 = ts[2 * p + 2] - ts[2 * p + 1];
        sPc[p] = make_float4(dt0, __builtin_sqrtf(dt0),
                             dt1, __builtin_sqrtf(dt1));
        const float sdv = SD_C * __builtin_sqrtf(t0) + 1e-4f;
        const float wx  = fast_rcp(6.0f * sdv);
        const float cx  = -MU_C * t0 * wx;
        const float qs  = wx * 1.4426950408889634f;   // 1/(6 sd ln2)
        sQc[p] = make_float4(cx, wx, qs, 0.0f);
    }
    for (int i = tid; i < NPAIRS * NCOEF; i += 256) sC[i] = C[i];
    __syncthreads();

    const int gid = blockIdx.x * 256 + tid;
    const float* np_ = noise + gid;

    float s   = 1.0f;
    float pnl = 0.0f;

    // preload chunk 0 noise (16 steps = 8 pairs)
    #define NLD0(k) float nn##k = np_[(size_t)(k) * BATCH];
    REP16(NLD0)
    #undef NLD0

    #pragma unroll 1
    for (int cc = 0; cc < NPAIRS / 8; ++cc) {
        const int cbase = cc * 8;              // pair offset
        const int pfo   = min((cc + 1) * 16, NSTEPS - 16);
        const float* nb = np_ + (size_t)pfo * BATCH;

        // prefetch next chunk's noise
        #define NPF(k) const float mm##k = nb[(size_t)(k) * BATCH];
        REP16(NPF)
        #undef NPF

        // per pair: exact 2-step s-chain + normalized query x
        #define CHP(p, e, o) \
            const float4 pc##p = sPc[cbase + p]; \
            const float4 qc##p = sQc[cbase + p]; \
            const float dW0##p  = nn##e * pc##p.y; \
            const float mil0##p = 0.5f * fmaf(dW0##p, dW0##p, -pc##p.x); \
            const float A0##p   = pc##p.x + dW0##p + mil0##p; \
            const float sv0##p  = s; \
            s = fmaf(s, A0##p, s); \
            const float dW1##p  = nn##o * pc##p.w; \
            const float mil1##p = 0.5f * fmaf(dW1##p, dW1##p, -pc##p.z); \
            const float A1##p   = pc##p.z + dW1##p + mil1##p; \
            const float sv1##p  = s; \
            s = fmaf(s, A1##p, s); \
            const float lg##p = __builtin_amdgcn_logf(sv0##p); \
            const float xq##p = fminf(1.0f, fmaxf(-1.0f, \
                fmaf(lg##p, qc##p.y, qc##p.x)));
        REPP(CHP)
        #undef CHP

        // per pair: dual Clenshaw (P and P'), pnl update + tangent step.
        // All locals uniquely suffixed (R22 NaN lesson).
        #define PNP(p, e, o) { \
            const float* cp_##p = &sC[(cbase + p) * NCOEF]; \
            float yb1_ = 0.0f, yb2_ = 0.0f, yd1_ = 0.0f, yd2_ = 0.0f; \
            const float xx2_ = xq##p + xq##p; \
            _Pragma("unroll") \
            for (int kk = NCOEF - 1; kk >= 1; --kk) { \
                const float yb0_ = fmaf(xx2_, yb1_, cp_##p[kk] - yb2_); \
                const float yd0_ = fmaf(xx2_, yd1_, fmaf(2.0f, yb1_, -yd2_)); \
                yb2_ = yb1_; yb1_ = yb0_; yd2_ = yd1_; yd1_ = yd0_; \
            } \
            const float hh0_ = fmaf(xq##p, yb1_, cp_##p[0] - yb2_); \
            const float qq0_ = fmaf(xq##p, yd1_, yb1_ - yd2_) * qc##p.z; \
            pnl = fmaf(sv0##p, fmaf(hh0_, A0##p, qq0_ * mil0##p), pnl); \
            const float hh1_ = fmaf(qq0_, A0##p, hh0_); \
            pnl = fmaf(sv1##p, fmaf(hh1_, A1##p, qq0_ * mil1##p), pnl); }
        REPP(PNP)
        #undef PNP

        // rotate prefetched noise
        #define NRT(k) nn##k = mm##k;
        REP16(NRT)
        #undef NRT
    }

    const float z = fmaxf(0.0f, s - 3.0f);
    const float d = z - pnl - wq[0];
    out[gid] = d * d;
}

// ---------------------------------------------------------------------------
// Fallback: direct per-thread MLP evaluation (R4 kernel) if ws too small.
// ---------------------------------------------------------------------------
__global__ __launch_bounds__(256, 3) void deep_hedging_direct(
    const float* __restrict__ noise, const float* __restrict__ ts,
    const float* __restrict__ w,
    const float* __restrict__ W1, const float* __restrict__ b1,
    const float* __restrict__ W2, const float* __restrict__ b2,
    const float* __restrict__ W3, const float* __restrict__ b3,
    float* __restrict__ out)
{
    __shared__ __align__(16) float sW1[64];
    __shared__ float sb1[32];
    __shared__ __align__(16) float sW2[1024];
    __shared__ float sb2[32];
    __shared__ float sW3[32];
    __shared__ float sb3w[2];
    __shared__ float sts[NSTEPS + 1];

    const int tid = threadIdx.x;
    for (int i = tid; i < 1024; i += 256) sW2[i] = W2[i];
    if (tid < 64) sW1[tid] = W1[tid];
    if (tid < 32) { sb1[tid] = b1[tid]; sb2[tid] = b2[tid]; sW3[tid] = W3[tid]; }
    if (tid == 0) { sb3w[0] = b3[0]; sb3w[1] = w[0]; }
    for (int i = tid; i < NSTEPS + 1; i += 256) sts[i] = ts[i];
    __syncthreads();

    const int gid = blockIdx.x * 256 + tid;
    const float* np_ = noise + gid;

    float s   = 1.0f;
    float pnl = 0.0f;
    const float b3v = sb3w[0];
    const float wv_ = sb3w[1];

    #pragma unroll 1
    for (int st = 0; st < NSTEPS; ++st) {
        int zr = 0;
        asm volatile("" : "+v"(zr));   // block LICM of weight loads
        const float2* W1r = (const float2*)sW1 + zr;
        const float*  B1  = sb1 + zr;
        const float4* W2r = (const float4*)sW2 + zr;
        const float*  B2  = sb2 + zr;
        const float*  W3r = sW3 + zr;

        const float t  = sts[st];
        const float dt = sts[st + 1] - t;
        const float dW = np_[(size_t)st * BATCH] * __builtin_sqrtf(dt);
        const float sd = s;

        float h, hacc;
        MLP_BODY(W1r, B1, W2r, B2, W3r, b3v, t, s, sd, h, hacc)
        const float hd = h * (1.0f - h) * hacc;

        const float mil = 0.5f * (dW * dW - dt);
        const float g1  = s * h;
        const float dg1 = fmaf(sd, h, s * hd);
        const float snew = s + s * dt + s * dW + sd * mil;
        pnl = pnl + g1 * dt + g1 * dW + dg1 * mil;
        s = snew;
    }

    const float z = fmaxf(0.0f, s - 3.0f);
    const float d = z - pnl - wv_;
    out[gid] = d * d;
}

extern "C" void kernel_launch(void* const* d_in, const int* in_sizes, int n_in,
                              void* d_out, int out_size, void* d_ws, size_t ws_size,
                              hipStream_t stream) {
    const float* noise = (const float*)d_in[0];
    const float* ts    = (const float*)d_in[1];
    const float* w     = (const float*)d_in[2];
    const float* W1    = (const float*)d_in[3];
    const float* b1    = (const float*)d_in[4];
    const float* W2    = (const float*)d_in[5];
    const float* b2    = (const float*)d_in[6];
    const float* W3    = (const float*)d_in[7];
    const float* b3    = (const float*)d_in[8];
    float* out = (float*)d_out;

    const size_t need = (size_t)NPAIRS * NCOEF * sizeof(float);   // 8 KB

    if (ws_size >= need) {
        float* C = (float*)d_ws;

        dim3 b(256);
        fit_kernel<<<dim3(NPAIRS / 16), b, 0, stream>>>(
            ts, W1, b1, W2, b2, W3, b3, C);
        path_kernel<<<dim3(BATCH / 256), b, 0, stream>>>(
            noise, ts, w, C, out);
    } else {
        dim3 grid(BATCH / 256), block(256);
        deep_hedging_direct<<<grid, block, 0, stream>>>(noise, ts, w, W1, b1,
                                                        W2, b2, W3, b3, out);
    }
}

// Round 24
// 61.574 us; speedup vs baseline: 1.0766x; 1.0766x over previous
//
#include <hip/hip_runtime.h>
#include <hip/hip_fp16.h>
#include <math.h>

#define BATCH 131072
#define NSTEPS 256
#define LGN 7
#define NPTS 128           // (1 << LGN)
#define ZSPAN 12.0f        // z in [-6, 6]
#define ZLO 6.0f
#define ZSCALE (NPTS / ZSPAN)      // entries per sigma (10.667)
#define DZ (ZSPAN / NPTS)          // 0.09375
#define MU_C 0.72134752044448170367f   // (mu - sigma^2/2)/ln2 = 0.5/ln2
#define SD_C 1.4426950408889634f       // sigma/ln2

using f32x2 = __attribute__((ext_vector_type(2))) float;

__device__ __forceinline__ float fast_exp(float x) {
    return __builtin_amdgcn_exp2f(x * 1.44269504088896340736f);
}
__device__ __forceinline__ float fast_rcp(float x) {
    return __builtin_amdgcn_rcpf(x);
}
__device__ __forceinline__ float sigmoidf_fast(float x) {
    return fast_rcp(1.0f + fast_exp(-x));
}

#define REP32(M) M(0) M(1) M(2) M(3) M(4) M(5) M(6) M(7) \
                 M(8) M(9) M(10) M(11) M(12) M(13) M(14) M(15) \
                 M(16) M(17) M(18) M(19) M(20) M(21) M(22) M(23) \
                 M(24) M(25) M(26) M(27) M(28) M(29) M(30) M(31)

#define REP16(M) M(0) M(1) M(2) M(3) M(4) M(5) M(6) M(7) \
                 M(8) M(9) M(10) M(11) M(12) M(13) M(14) M(15)

// Shared MLP+tangent body (see R4). Produces h and pre-sigmoid tangent acc.
#define MLP_BODY(W1r, B1, W2r, B2, W3r, b3v, t, s, sd, H, HACC) \
    { \
        const float __t = (t), __s = (s), __sd = (sd); \
        f32x2 acc2 = {(b3v), 0.0f}; \
        REP32(MLP_L1) \
        REP32(MLP_ROW) \
        H = sigmoidf_fast(acc2.x); \
        HACC = acc2.y; \
    }

#define MLP_L1(j) f32x2 at##j; { \
    const float2 wv = W1r[j]; \
    const float z  = fmaf(wv.x, __t, fmaf(wv.y, __s, B1[j])); \
    const float zd = wv.y * __sd; \
    const float sg = sigmoidf_fast(z); \
    const float da = sg * (1.0f + z * (1.0f - sg)); \
    at##j = (f32x2){z * sg, da * zd}; }

#define MLP_ROW(j) { \
    const float4 q0 = W2r[(j) * 8 + 0]; \
    const float4 q1 = W2r[(j) * 8 + 1]; \
    const float4 q2 = W2r[(j) * 8 + 2]; \
    const float4 q3 = W2r[(j) * 8 + 3]; \
    const float4 q4 = W2r[(j) * 8 + 4]; \
    const float4 q5 = W2r[(j) * 8 + 5]; \
    const float4 q6 = W2r[(j) * 8 + 6]; \
    const float4 q7 = W2r[(j) * 8 + 7]; \
    f32x2 zza = {B2[j], 0.0f}; \
    f32x2 zzb = {0.0f, 0.0f}; \
    zza += (f32x2){q0.x, q0.x} * at0;  zzb += (f32x2){q0.y, q0.y} * at1; \
    zza += (f32x2){q0.z, q0.z} * at2;  zzb += (f32x2){q0.w, q0.w} * at3; \
    zza += (f32x2){q1.x, q1.x} * at4;  zzb += (f32x2){q1.y, q1.y} * at5; \
    zza += (f32x2){q1.z, q1.z} * at6;  zzb += (f32x2){q1.w, q1.w} * at7; \
    zza += (f32x2){q2.x, q2.x} * at8;  zzb += (f32x2){q2.y, q2.y} * at9; \
    zza += (f32x2){q2.z, q2.z} * at10; zzb += (f32x2){q2.w, q2.w} * at11; \
    zza += (f32x2){q3.x, q3.x} * at12; zzb += (f32x2){q3.y, q3.y} * at13; \
    zza += (f32x2){q3.z, q3.z} * at14; zzb += (f32x2){q3.w, q3.w} * at15; \
    zza += (f32x2){q4.x, q4.x} * at16; zzb += (f32x2){q4.y, q4.y} * at17; \
    zza += (f32x2){q4.z, q4.z} * at18; zzb += (f32x2){q4.w, q4.w} * at19; \
    zza += (f32x2){q5.x, q5.x} * at20; zzb += (f32x2){q5.y, q5.y} * at21; \
    zza += (f32x2){q5.z, q5.z} * at22; zzb += (f32x2){q5.w, q5.w} * at23; \
    zza += (f32x2){q6.x, q6.x} * at24; zzb += (f32x2){q6.y, q6.y} * at25; \
    zza += (f32x2){q6.z, q6.z} * at26; zzb += (f32x2){q6.w, q6.w} * at27; \
    zza += (f32x2){q7.x, q7.x} * at28; zzb += (f32x2){q7.y, q7.y} * at29; \
    zza += (f32x2){q7.z, q7.z} * at30; zzb += (f32x2){q7.w, q7.w} * at31; \
    const f32x2 zzt = zza + zzb; \
    const float zv  = zzt.x; \
    const float sg  = sigmoidf_fast(zv); \
    const float da  = sg * (1.0f + zv * (1.0f - sg)); \
    const float w3  = W3r[j]; \
    acc2 += (f32x2){w3, w3} * (f32x2){zv * sg, da * zzt.y}; \
}

// ---------------------------------------------------------------------------
// Kernel 1: evaluate packed half2{h, q} at standardized grid points and write
// DIRECTLY into the paired table (each value lands in T2[st][k].x and
// T2[st][k-1].y).
// ---------------------------------------------------------------------------
__global__ __launch_bounds__(256) void table_eval_kernel(
    const float* __restrict__ ts,
    const float* __restrict__ W1, const float* __restrict__ b1,
    const float* __restrict__ W2, const float* __restrict__ b2,
    const float* __restrict__ W3, const float* __restrict__ b3,
    unsigned int* __restrict__ W)      // = (unsigned int*)T2, 2 words/entry
{
    __shared__ __align__(16) float sW1[64];
    __shared__ float sb1[32];
    __shared__ __align__(16) float sW2[1024];
    __shared__ float sb2[32];
    __shared__ float sW3[32];
    __shared__ float sb3[1];

    const int tid = threadIdx.x;
    for (int i = tid; i < 1024; i += 256) sW2[i] = W2[i];
    if (tid < 64) sW1[tid] = W1[tid];
    if (tid < 32) { sb1[tid] = b1[tid]; sb2[tid] = b2[tid]; sW3[tid] = W3[tid]; }
    if (tid == 0) sb3[0] = b3[0];
    __syncthreads();

    const float2* W1r = (const float2*)sW1;
    const float*  B1  = sb1;
    const float4* W2r = (const float4*)sW2;
    const float*  B2  = sb2;
    const float*  W3r = sW3;
    const float   b3v = sb3[0];

    const int gid = blockIdx.x * 256 + tid;
    const int st = gid >> LGN;
    const int k  = gid & (NPTS - 1);

    const float t  = ts[st];
    const float mu = MU_C * t;
    const float sd = SD_C * __builtin_sqrtf(t) + 1e-4f;
    const float zz = fmaf((float)k, DZ, -ZLO);
    const float s  = __builtin_amdgcn_exp2f(fmaf(zz, sd, mu));

    float h, hacc;
    MLP_BODY(W1r, B1, W2r, B2, W3r, b3v, t, s, 1.0f, h, hacc)

    const float q = h * (1.0f - h) * hacc * s;   // s * dh/ds (Hermite tangent)
    __half2 p = __floats2half2_rn(h, q);
    const unsigned int pv = *(unsigned int*)&p;

    W[2 * gid] = pv;                       // T2[st][k].x
    if (k > 0)         W[2 * gid - 1] = pv;  // T2[st][k-1].y
    if (k == NPTS - 1) W[2 * gid + 1] = pv;  // row-end clamp
}

// ---------------------------------------------------------------------------
// Kernel 2: SDE path integration.  32 steps per iteration (two 16-step CH
// blocks back-to-back, 32 noise prefetches, one pin, two PN blocks).
// Cubic Hermite for h, linear for q.  Best-measured configuration (R17:
// 61.77 us total, absmax 1.0).
// ---------------------------------------------------------------------------
__global__ __launch_bounds__(256, 1) void path_kernel(
    const float* __restrict__ noise,   // (NSTEPS, BATCH)
    const float* __restrict__ ts,      // (NSTEPS+1)
    const float* __restrict__ wq,      // scalar
    const uint2* __restrict__ T2,      // (NSTEPS, NPTS) paired entries
    float* __restrict__ out)           // (BATCH)
{
    __shared__ float4 sdt4[NSTEPS];    // {dt, sqrt(dt), c', w'}: u = x*w' + c'
    __shared__ float  scr[NSTEPS];     // cr = ln2 / w' (Hermite tangent scale)
    const int tid = threadIdx.x;
    if (tid < NSTEPS) {
        const float t0  = ts[tid];
        const float dtv = ts[tid + 1] - t0;
        const float sdv = SD_C * __builtin_sqrtf(t0) + 1e-4f;
        const float wp  = fast_rcp(sdv) * ZSCALE;
        const float cp  = ZLO * ZSCALE - MU_C * t0 * wp;
        sdt4[tid] = make_float4(dtv, __builtin_sqrtf(dtv), cp, wp);
        scr[tid]  = 0.69314718056f * fast_rcp(wp);
    }
    __syncthreads();

    const int gid = blockIdx.x * 256 + tid;
    const float* np_ = noise + gid;
    const float umax = (float)NPTS - 1.001f;

    float s   = 1.0f;
    float pnl = 0.0f;

    // preload noise for steps 0-15 (set A) and 16-31 (set B)
    #define NL0(k) float nA##k = np_[(size_t)(k) * BATCH]; \
                   float nB##k = np_[(size_t)(16 + k) * BATCH];
    REP16(NL0)
    #undef NL0

    // per-step: s-chain + gather issue + P/Q precompute
    #define CHK(k, G, NPv, BASE) \
        const float4 dq##G##k = sdt4[(BASE) + k]; \
        const float dW##G##k  = NPv##k * dq##G##k.y; \
        const float mil##G##k = 0.5f * fmaf(dW##G##k, dW##G##k, -dq##G##k.x); \
        const float Af##G##k  = dq##G##k.x + dW##G##k + mil##G##k; \
        const float sv##G##k  = s; \
        s = fmaf(s, Af##G##k, s); \
        const float P##G##k = sv##G##k * Af##G##k; \
        const float Q##G##k = sv##G##k * mil##G##k; \
        const float x##G##k = __builtin_amdgcn_logf(sv##G##k); \
        const float u##G##k = \
            fminf(fmaxf(fmaf(x##G##k, dq##G##k.w, dq##G##k.z), 0.0f), umax); \
        const int   i0##G##k = (int)u##G##k; \
        const float f##G##k  = u##G##k - (float)i0##G##k; \
        unsigned long long E##G##k = \
            ((const unsigned long long*)(T2 + ((size_t)((BASE) + k) << LGN)))[i0##G##k];

    // noise prefetch (rows PFB..PFB+15 into set NPv; consumed next iteration)
    #define NPF(k, NPv, PFB) NPv##k = np_[(size_t)((PFB) + k) * BATCH];

    // consume: cubic Hermite for h, linear for q; pnl += hh*P + qq*Q
    #define PNK(k, G, BASE) { \
        const uint2 eu = __builtin_bit_cast(uint2, E##G##k); \
        const float2 a0 = __half22float2(*(const __half2*)&eu.x); \
        const float2 a1 = __half22float2(*(const __half2*)&eu.y); \
        const float cr = scr[(BASE) + k]; \
        const float uu = f##G##k; \
        const float m  = uu * uu; \
        const float n  = m * uu; \
        const float dh = a1.x - a0.x; \
        const float ba = fmaf(-2.0f, n, 3.0f * m);            /* 3u^2-2u^3 */ \
        const float bb = fmaf(-2.0f, m, uu) + n;              /* u^3-2u^2+u */ \
        const float bc = n - m;                               /* u^3-u^2 */ \
        const float hh = fmaf(dh, ba, a0.x) + cr * fmaf(a0.y, bb, a1.y * bc); \
        const float qq = fmaf(uu, a1.y - a0.y, a0.y); \
        pnl = fmaf(hh, P##G##k, fmaf(qq, Q##G##k, pnl)); }

    #define CHA(k) CHK(k, A, nA, baseA)
    #define CHB(k) CHK(k, B, nB, baseB)
    #define NPA(k) NPF(k, nA, pfA)
    #define NPB(k) NPF(k, nB, pfB)
    #define PNA(k) PNK(k, A, baseA)
    #define PNB(k) PNK(k, B, baseB)

    #pragma unroll 1
    for (int cc = 0; cc < NSTEPS / 32; ++cc) {
        const int baseA = cc * 32;
        const int baseB = cc * 32 + 16;
        const int pfA = min(baseA + 32, NSTEPS - 16);
        const int pfB = min(baseB + 32, NSTEPS - 16);

        REP16(CHA)
        REP16(CHB)
        __builtin_amdgcn_sched_barrier(0);
        REP16(NPA)
        REP16(NPB)
        asm volatile("" : "+v"(EA0), "+v"(EA1), "+v"(EA2),  "+v"(EA3),
                          "+v"(EA4), "+v"(EA5), "+v"(EA6),  "+v"(EA7));
        asm volatile("" : "+v"(EA8), "+v"(EA9), "+v"(EA10), "+v"(EA11),
                          "+v"(EA12),"+v"(EA13),"+v"(EA14), "+v"(EA15));
        asm volatile("" : "+v"(EB0), "+v"(EB1), "+v"(EB2),  "+v"(EB3),
                          "+v"(EB4), "+v"(EB5), "+v"(EB6),  "+v"(EB7));
        asm volatile("" : "+v"(EB8), "+v"(EB9), "+v"(EB10), "+v"(EB11),
                          "+v"(EB12),"+v"(EB13),"+v"(EB14), "+v"(EB15));
        __builtin_amdgcn_sched_barrier(0);
        REP16(PNA)
        REP16(PNB)
    }

    #undef CHA
    #undef CHB
    #undef NPA
    #undef NPB
    #undef PNA
    #undef PNB
    #undef PNK
    #undef NPF
    #undef CHK

    const float z = fmaxf(0.0f, s - 3.0f);
    const float d = z - pnl - wq[0];
    out[gid] = d * d;
}

// ---------------------------------------------------------------------------
// Fallback: direct per-thread MLP evaluation (R4 kernel) if ws too small.
// ---------------------------------------------------------------------------
__global__ __launch_bounds__(256, 3) void deep_hedging_direct(
    const float* __restrict__ noise, const float* __restrict__ ts,
    const float* __restrict__ w,
    const float* __restrict__ W1, const float* __restrict__ b1,
    const float* __restrict__ W2, const float* __restrict__ b2,
    const float* __restrict__ W3, const float* __restrict__ b3,
    float* __restrict__ out)
{
    __shared__ __align__(16) float sW1[64];
    __shared__ float sb1[32];
    __shared__ __align__(16) float sW2[1024];
    __shared__ float sb2[32];
    __shared__ float sW3[32];
    __shared__ float sb3w[2];
    __shared__ float sts[NSTEPS + 1];

    const int tid = threadIdx.x;
    for (int i = tid; i < 1024; i += 256) sW2[i] = W2[i];
    if (tid < 64) sW1[tid] = W1[tid];
    if (tid < 32) { sb1[tid] = b1[tid]; sb2[tid] = b2[tid]; sW3[tid] = W3[tid]; }
    if (tid == 0) { sb3w[0] = b3[0]; sb3w[1] = w[0]; }
    for (int i = tid; i < NSTEPS + 1; i += 256) sts[i] = ts[i];
    __syncthreads();

    const int gid = blockIdx.x * 256 + tid;
    const float* np_ = noise + gid;

    float s   = 1.0f;
    float pnl = 0.0f;
    const float b3v = sb3w[0];
    const float wv_ = sb3w[1];

    #pragma unroll 1
    for (int st = 0; st < NSTEPS; ++st) {
        int zr = 0;
        asm volatile("" : "+v"(zr));   // block LICM of weight loads
        const float2* W1r = (const float2*)sW1 + zr;
        const float*  B1  = sb1 + zr;
        const float4* W2r = (const float4*)sW2 + zr;
        const float*  B2  = sb2 + zr;
        const float*  W3r = sW3 + zr;

        const float t  = sts[st];
        const float dt = sts[st + 1] - t;
        const float dW = np_[(size_t)st * BATCH] * __builtin_sqrtf(dt);
        const float sd = s;

        float h, hacc;
        MLP_BODY(W1r, B1, W2r, B2, W3r, b3v, t, s, sd, h, hacc)
        const float hd = h * (1.0f - h) * hacc;

        const float mil = 0.5f * (dW * dW - dt);
        const float g1  = s * h;
        const float dg1 = fmaf(sd, h, s * hd);
        const float snew = s + s * dt + s * dW + sd * mil;
        pnl = pnl + g1 * dt + g1 * dW + dg1 * mil;
        s = snew;
    }

    const float z = fmaxf(0.0f, s - 3.0f);
    const float d = z - pnl - wv_;
    out[gid] = d * d;
}

extern "C" void kernel_launch(void* const* d_in, const int* in_sizes, int n_in,
                              void* d_out, int out_size, void* d_ws, size_t ws_size,
                              hipStream_t stream) {
    const float* noise = (const float*)d_in[0];
    const float* ts    = (const float*)d_in[1];
    const float* w     = (const float*)d_in[2];
    const float* W1    = (const float*)d_in[3];
    const float* b1    = (const float*)d_in[4];
    const float* W2    = (const float*)d_in[5];
    const float* b2    = (const float*)d_in[6];
    const float* W3    = (const float*)d_in[7];
    const float* b3    = (const float*)d_in[8];
    float* out = (float*)d_out;

    const size_t nA   = (size_t)NSTEPS * NPTS;           // entries
    const size_t need = nA * sizeof(uint2);              // 256 KB

    if (ws_size >= need) {
        uint2* T2 = (uint2*)d_ws;

        dim3 b(256);
        table_eval_kernel<<<dim3(nA / 256), b, 0, stream>>>(
            ts, W1, b1, W2, b2, W3, b3, (unsigned int*)T2);
        path_kernel<<<dim3(BATCH / 256), b, 0, stream>>>(
            noise, ts, w, T2, out);
    } else {
        dim3 grid(BATCH / 256), block(256);
        deep_hedging_direct<<<grid, block, 0, stream>>>(noise, ts, w, W1, b1,
                                                        W2, b2, W3, b3, out);
    }
}